// Round 1
// baseline (444.029 us; speedup 1.0000x reference)
//
#include <hip/hip_runtime.h>

namespace {
constexpr int BATCH = 8;
constexpr int SPB = 2;               // samples per block: waves 0-3 -> s0, waves 4-7 -> s1
constexpr int NBLK = BATCH / SPB;    // 4 blocks; 8 waves/CU = 2 waves/SIMD (latency hiding)
constexpr int WIDTH = 48;
constexpr int N = WIDTH * WIDTH;   // 2304
constexpr int SW = 64;             // slot-row stride: 16 slots x 4 floats (16B each)
constexpr int FH = 54;             // 48 + 6 halo rows
constexpr int NT = 256 * SPB;      // 512 threads; per-sample layout identical to 256-thread kernel
constexpr int WPS = 4;             // waves per sample
constexpr float EPS = 1e-8f;
constexpr int MAX_ITERS = 250;
constexpr float TOLSQ = 1e-10f;    // (1e-5)^2
// Separable square-kernel weights e^{-5t}; in-loop kernel K' = eps*J +
// e^{-5|dr|}e^{-5|dc|} (|dr|,|dc|<=3). Perturbation vs true K verified R10/R11:
// absmax 1.56e-2 vs 4.53e-2 threshold. Per-pixel numerics identical to the
// 1-sample/block kernel (stid = tid&255 reproduces its tid exactly).
constexpr float W1 = 6.7379470e-3f;  // e^-5
constexpr float W2 = 4.5399930e-5f;  // e^-10
constexpr float W3 = 3.0590232e-7f;  // e^-15
}

// DPP lane shifts within each 16-lane row; bound_ctrl=true zero-fills at the
// DPP-row boundary, which coincides exactly with the grid's column edge
// (16 col-groups per grid row), reproducing the zero column halo.
__device__ __forceinline__ float dpp_shr1(float v) {  // lane n <- lane n-1
  return __int_as_float(__builtin_amdgcn_update_dpp(
      0, __float_as_int(v), 0x111, 0xf, 0xf, true));
}
__device__ __forceinline__ float dpp_shl1(float v) {  // lane n <- lane n+1
  return __int_as_float(__builtin_amdgcn_update_dpp(
      0, __float_as_int(v), 0x101, 0xf, 0xf, true));
}
template <int S>
__device__ __forceinline__ float dpp_shr(float v) {   // row_shr:S, zero-fill
  return __int_as_float(__builtin_amdgcn_update_dpp(
      0, __float_as_int(v), 0x110 | S, 0xf, 0xf, true));
}

// Wave-wide sum on the VALU pipe only (no DS-pipe shuffles).
__device__ __forceinline__ float wave_sum(float v) {
  v += dpp_shr<1>(v);
  v += dpp_shr<2>(v);
  v += dpp_shr<4>(v);
  v += dpp_shr<8>(v);
  const float a = __int_as_float(__builtin_amdgcn_readlane(__float_as_int(v), 15));
  const float b = __int_as_float(__builtin_amdgcn_readlane(__float_as_int(v), 31));
  const float c = __int_as_float(__builtin_amdgcn_readlane(__float_as_int(v), 47));
  const float d = __int_as_float(__builtin_amdgcn_readlane(__float_as_int(v), 63));
  return (a + b) + (c + d);
}

__device__ __forceinline__ float sum4(const float* buf) {
  const float4 a = *(const float4*)buf;  // one broadcast b128, conflict-free
  return (a.x + a.y) + (a.z + a.w);
}

// Horizontal 7-tap over one grid row's 1x3 values; neighbor columns come from
// adjacent lanes' registers via DPP (6 DPP + ~12 VALU, no LDS).
__device__ __forceinline__ void horiz7(const float t[3], float H[3]) {
  float rowv[9];  // rowv[i] = value at column c0 + i - 3
  rowv[3] = t[0]; rowv[4] = t[1]; rowv[5] = t[2];
#pragma unroll
  for (int j = 0; j < 3; ++j) {
    rowv[j] = dpp_shr1(t[j]);      // left neighbor's cols c0-3..c0-1
    rowv[6 + j] = dpp_shl1(t[j]);  // right neighbor's cols c0+3..c0+5
  }
#pragma unroll
  for (int k = 0; k < 3; ++k) {
    H[k] = rowv[k + 3] + W1 * (rowv[k + 2] + rowv[k + 4]) +
           W2 * (rowv[k + 1] + rowv[k + 5]) + W3 * (rowv[k] + rowv[k + 6]);
  }
}

// Vertical 7-tap over the H-field for a 3-row tile: 6 halo rows via single
// ds_read_b128 each (2 reads per output row); own 3 rows from registers.
__device__ __forceinline__ void vert7x3(const float* __restrict__ hbuf, int ip,
                                        const float* __restrict__ own,  // [9]
                                        float* __restrict__ acc) {      // [9]
  const float4 m3 = *(const float4*)(hbuf + ip - 3 * SW);  // row r0-3
  const float4 m2 = *(const float4*)(hbuf + ip - 2 * SW);
  const float4 m1 = *(const float4*)(hbuf + ip - 1 * SW);
  const float4 p3 = *(const float4*)(hbuf + ip + 3 * SW);  // row r0+3
  const float4 p4 = *(const float4*)(hbuf + ip + 4 * SW);
  const float4 p5 = *(const float4*)(hbuf + ip + 5 * SW);
  // h[j][k]: H at row r0-3+j (j=0..8), col c0+k
  float h[9][3];
  h[0][0] = m3.x; h[0][1] = m3.y; h[0][2] = m3.z;
  h[1][0] = m2.x; h[1][1] = m2.y; h[1][2] = m2.z;
  h[2][0] = m1.x; h[2][1] = m1.y; h[2][2] = m1.z;
#pragma unroll
  for (int r = 0; r < 3; ++r)
#pragma unroll
    for (int k = 0; k < 3; ++k) h[3 + r][k] = own[r * 3 + k];
  h[6][0] = p3.x; h[6][1] = p3.y; h[6][2] = p3.z;
  h[7][0] = p4.x; h[7][1] = p4.y; h[7][2] = p4.z;
  h[8][0] = p5.x; h[8][1] = p5.y; h[8][2] = p5.z;
#pragma unroll
  for (int r = 0; r < 3; ++r) {
#pragma unroll
    for (int k = 0; k < 3; ++k) {
      acc[r * 3 + k] = h[3 + r][k] + W1 * (h[2 + r][k] + h[4 + r][k]) +
                       W2 * (h[1 + r][k] + h[5 + r][k]) +
                       W3 * (h[r][k] + h[6 + r][k]);
    }
  }
}

// Exact diamond (L1 radius 3) conv for the EPILOGUE distance term, weights
// d*(e^{-5d}-eps), on raw v held as a 3-row tile (own rows in regs c[9],
// halo rows via b128 slot reads, horizontal extension via DPP). One-time.
__device__ __forceinline__ void conv_dist3(const float* __restrict__ pad, int ip,
                                           const float* __restrict__ c,
                                           float* __restrict__ out) {
  float acc[9];
#pragma unroll
  for (int i = 0; i < 9; ++i) acc[i] = 0.f;
#pragma unroll
  for (int rho = -3; rho <= 5; ++rho) {  // input row relative to tile row 0
    float t[3];
    if (rho >= 0 && rho <= 2) {
      t[0] = c[rho * 3]; t[1] = c[rho * 3 + 1]; t[2] = c[rho * 3 + 2];
    } else {
      const float4 q = *(const float4*)(pad + ip + rho * SW);
      t[0] = q.x; t[1] = q.y; t[2] = q.z;
    }
    float rowv[9];
    rowv[3] = t[0]; rowv[4] = t[1]; rowv[5] = t[2];
#pragma unroll
    for (int j = 0; j < 3; ++j) {
      rowv[j] = dpp_shr1(t[j]);
      rowv[6 + j] = dpp_shl1(t[j]);
    }
#pragma unroll
    for (int r = 0; r < 3; ++r) {
      int d = rho - r; d = d < 0 ? -d : d;
      if (d > 3) continue;
#pragma unroll
      for (int k = 0; k < 3; ++k) {
#pragma unroll
        for (int m = -3; m <= 3; ++m) {
          if (m < -(3 - d) || m > (3 - d)) continue;
          const int dist = d + (m < 0 ? -m : m);
          if (dist == 0) continue;
          const float wgt = (dist == 1) ? 6.7379370e-3f   // 1*(e^-5  - 1e-8)
                          : (dist == 2) ? 9.0779860e-5f   // 2*(e^-10 - 1e-8)
                                        : 8.8770696e-7f;  // 3*(e^-15 - 1e-8)
          acc[r * 3 + k] += wgt * rowv[k + m + 3];
        }
      }
    }
  }
#pragma unroll
  for (int i = 0; i < 9; ++i) out[i] = acc[i];
}

__global__ __launch_bounds__(NT, 1) void sinkhorn48(const float* __restrict__ x,
                                                    const float* __restrict__ y,
                                                    float* __restrict__ out) {
  // Two independent samples per block, one per 4-wave group. Barriers are
  // shared (both samples run the same schedule), data/reductions are per-sample.
  __shared__ alignas(16) float bufU[SPB][FH * SW];  // H-field of u
  __shared__ alignas(16) float bufV[SPB][FH * SW];  // H-field of v; raw v in epilogue
  __shared__ alignas(16) float rA[SPB][4];  // Su partials / x-sum / dist partials
  __shared__ alignas(16) float rB[SPB][4];  // Sv partials / y-sum
  __shared__ alignas(16) float rC[SPB][4];  // diff^2 partials (every 8th iter)
  __shared__ float vr[SPB][WIDTH];
  __shared__ float vc[SPB][WIDTH];

  const int tid = threadIdx.x;
  const int s = tid >> 8;             // sample within block (wave group)
  const int stid = tid & 255;         // per-sample thread id == old kernel's tid
  const int r0 = (stid >> 4) * 3;     // 16 row-groups of 3 rows
  const int tc = stid & 15;           // slot (column-group) index
  const int c0 = tc * 3;              // 3 adjacent columns per thread
  const int ip = (r0 + 3) * SW + tc * 4;  // 16B-aligned slot base (row r0)
  const int wid = stid >> 6;          // wave index within the sample, 0..3
  const int lane = tid & 63;

  float* const bu = bufU[s];
  float* const bv = bufV[s];
  float* const ra = rA[s];
  float* const rb = rB[s];

  // Zero both fields of both samples (halo rows + pad dwords must stay zero).
  for (int i = tid; i < SPB * FH * SW; i += NT) {
    (&bufU[0][0])[i] = 0.f;
    (&bufV[0][0])[i] = 0.f;
  }

  // Load this thread's 3x3 pixels of its sample's images into registers.
  const float* xb = x + (blockIdx.x * SPB + s) * N;
  const float* yb = y + (blockIdx.x * SPB + s) * N;
  float xr[9], yr[9];
#pragma unroll
  for (int r = 0; r < 3; ++r)
#pragma unroll
    for (int k = 0; k < 3; ++k) {
      xr[r * 3 + k] = xb[(r0 + r) * WIDTH + c0 + k];
      yr[r * 3 + k] = yb[(r0 + r) * WIDTH + c0 + k];
    }
  {
    float sx = 0.f, sy = 0.f;
#pragma unroll
    for (int i = 0; i < 9; ++i) { sx += xr[i]; sy += yr[i]; }
    sx = wave_sum(sx); sy = wave_sum(sy);
    if (lane == 0) { ra[wid] = sx; rb[wid] = sy; }
  }
  __syncthreads();  // B0: publishes rA/rB partials + zeroed fields
  const float irx = __builtin_amdgcn_rcpf(sum4(ra));
  const float iry = __builtin_amdgcn_rcpf(sum4(rb));
#pragma unroll
  for (int i = 0; i < 9; ++i) { xr[i] *= irx; yr[i] *= iry; }

  float ur[9], hu[9], hv[9];
#pragma unroll
  for (int i = 0; i < 9; ++i) ur[i] = 1.0f / (float)N;
#pragma unroll
  for (int r = 0; r < 3; ++r) horiz7(ur + r * 3, hu + r * 3);
#pragma unroll
  for (int r = 0; r < 3; ++r)
    *(float4*)(bu + ip + r * SW) = make_float4(hu[r * 3], hu[r * 3 + 1], hu[r * 3 + 2], 0.f);
  __syncthreads();  // B1: separates rA/rB reads above from rewrite below
  if (stid < WPS) { ra[stid] = 1.0f / (float)WPS; rC[s][stid] = 1.0f; }
  __syncthreads();  // B2: publishes rA (Su(u0)=1), rC dummy, bufU interior

  // Per-sample freeze flag (reference's `done` mask). Break only when BOTH
  // samples have converged so the shared barrier schedule stays uniform.
  bool act = true;

  float cc[9], vv[9];
  for (int iter = 0; iter < MAX_ITERS; ++iter) {
    const float Su = sum4(ra);   // published at last barrier; hides in vert7
    vert7x3(bu, ip, hu, cc);     // (u @ K')_local
    // Convergence check amortized 8x (R3 timing: never fires in 250 iters ->
    // byte-identical output; if it fired, frozen-u semantics match reference).
    if ((iter & 7) == 0 && iter >= 8) {
      const float d0 = sum4(rC[0]);
      const float d1 = sum4(rC[1]);
      if (d0 < TOLSQ && d1 < TOLSQ) break;
      act = ((s == 0) ? d0 : d1) >= TOLSQ;
    }
    if (act) {
      const float base = EPS * Su;
      float pv = 0.f;
#pragma unroll
      for (int i = 0; i < 9; ++i) {
        vv[i] = yr[i] * __builtin_amdgcn_rcpf(base + cc[i]);
        pv += vv[i];
      }
#pragma unroll
      for (int r = 0; r < 3; ++r) horiz7(vv + r * 3, hv + r * 3);
#pragma unroll
      for (int r = 0; r < 3; ++r)
        *(float4*)(bv + ip + r * SW) = make_float4(hv[r * 3], hv[r * 3 + 1], hv[r * 3 + 2], 0.f);
      pv = wave_sum(pv);
      if (lane == 0) rb[wid] = pv;
    }
    __syncthreads();  // A: publishes bufV (H of v) + Sv partials

    const float Sv = sum4(rb);  // hides behind vert7 reads
    vert7x3(bv, ip, hv, cc);
    if (act) {
      const float base2 = EPS * Sv;
      float psu = 0.f;
      if ((iter & 7) == 7) {
        float pd = 0.f;
#pragma unroll
        for (int i = 0; i < 9; ++i) {
          const float un = xr[i] * __builtin_amdgcn_rcpf(base2 + cc[i]);
          const float d = ur[i] - un;
          ur[i] = un;
          psu += un;
          pd += d * d;
        }
        pd = wave_sum(pd);
        if (lane == 0) rC[s][wid] = pd;
      } else {
#pragma unroll
        for (int i = 0; i < 9; ++i) {
          const float un = xr[i] * __builtin_amdgcn_rcpf(base2 + cc[i]);
          ur[i] = un;
          psu += un;
        }
      }
#pragma unroll
      for (int r = 0; r < 3; ++r) horiz7(ur + r * 3, hu + r * 3);
#pragma unroll
      for (int r = 0; r < 3; ++r)
        *(float4*)(bu + ip + r * SW) = make_float4(hu[r * 3], hu[r * 3 + 1], hu[r * 3 + 2], 0.f);
      psu = wave_sum(psu);
      if (lane == 0) ra[wid] = psu;
    }
    __syncthreads();  // B: publishes bufU (H of u) + Su (+diff) partials
  }

  // Final v from converged u (rA/bufU/hu consistent on both exit paths).
  const float SuF = sum4(ra);
  vert7x3(bu, ip, hu, cc);
  const float base = EPS * SuF;
#pragma unroll
  for (int i = 0; i < 9; ++i) vv[i] = yr[i] * __builtin_amdgcn_rcpf(base + cc[i]);
#pragma unroll
  for (int r = 0; r < 3; ++r)  // raw v for the epilogue (halo rows still zero)
    *(float4*)(bv + ip + r * SW) = make_float4(vv[r * 3], vv[r * 3 + 1], vv[r * 3 + 2], 0.f);
  __syncthreads();

  // Row/col marginals of v for the separable eps*(C @ v) term (one-time).
  if (stid < WIDTH) {
    float sm = 0.f;
    const float4* rp = (const float4*)(bv + (stid + 3) * SW);
    for (int t = 0; t < 16; ++t) { const float4 q = rp[t]; sm += q.x + q.y + q.z; }
    vr[s][stid] = sm;
  } else if (stid >= 64 && stid < 64 + WIDTH) {
    const int c = stid - 64;
    float sm = 0.f;
    const float* cp = bv + 3 * SW + (c / 3) * 4 + (c % 3);
    for (int r = 0; r < WIDTH; ++r) sm += cp[r * SW];
    vc[s][c] = sm;
  }
  __syncthreads();

  // dist_b = sum_j u_j * ( eps*(Cv)_j + distance-weighted local conv ) — exact.
  float aD[9];
  conv_dist3(bv, ip, vv, aD);
  float part = 0.f;
#pragma unroll
  for (int r = 0; r < 3; ++r) {
    const int rr = r0 + r;
    float cvr = 0.f;
    for (int q = 0; q < WIDTH; ++q) cvr += vr[s][q] * fabsf((float)(q - rr));
#pragma unroll
    for (int k = 0; k < 3; ++k) {
      const int ccol = c0 + k;
      float cvc = 0.f;
      for (int q = 0; q < WIDTH; ++q) cvc += vc[s][q] * fabsf((float)(q - ccol));
      part += ur[r * 3 + k] * (EPS * (cvr + cvc) + aD[r * 3 + k]);
    }
  }
  {
    const float p = wave_sum(part);
    if (lane == 0) ra[wid] = p;  // WAR on rA separated by the barriers above
  }
  __syncthreads();
  if (stid == 0) out[blockIdx.x * SPB + s] = sum4(ra);
}

extern "C" void kernel_launch(void* const* d_in, const int* in_sizes, int n_in,
                              void* d_out, int out_size, void* d_ws, size_t ws_size,
                              hipStream_t stream) {
  const float* x = (const float*)d_in[0];
  const float* y = (const float*)d_in[1];
  float* out = (float*)d_out;
  sinkhorn48<<<NBLK, NT, 0, stream>>>(x, y, out);
}

// Round 4
// 310.915 us; speedup vs baseline: 1.4281x; 1.4281x over previous
//
#include <hip/hip_runtime.h>

namespace {
constexpr int BATCH = 8;
constexpr int WIDTH = 48;
constexpr int N = WIDTH * WIDTH;   // 2304
constexpr int SW = 64;             // slot-row stride: 16 slots x 4 floats (16B each)
constexpr int FH = 54;             // 48 + 6 halo rows (radius-3 kept for epilogue conv)
constexpr int NT = 256;            // 4 waves (1/SIMD); 3x3 tile/thread
constexpr int NWAVE = NT / 64;     // 4
constexpr float EPS = 1e-8f;
constexpr int MAX_ITERS = 250;
// In-loop kernel K' = eps*J + e^{-5|dr|}e^{-5|dc|} with |dr|,|dc|<=2.
// eps*J is implemented EXACTLY as rank-1: (eps*J*u)_i = eps*(sum u)  -- this
// keeps global connectivity / dual boundedness (R3 post-mortem: dropping it
// diverges). vs the R0-verified radius-3 kernel this only shrinks the
// distance-3 ring entries from e^-15+eps to eps (~1e-6 relative row mass);
// fixed-point shift ~1e-6 relative. Epilogue distance formula remains EXACT.
constexpr float W1 = 6.7379470e-3f;  // e^-5
constexpr float W2 = 4.5399930e-5f;  // e^-10
}

// DPP lane shifts within each 16-lane row; bound_ctrl=true zero-fills at the
// DPP-row boundary, which coincides exactly with the grid's column edge
// (16 col-groups per grid row), reproducing the zero column halo.
__device__ __forceinline__ float dpp_shr1(float v) {  // lane n <- lane n-1
  return __int_as_float(__builtin_amdgcn_update_dpp(
      0, __float_as_int(v), 0x111, 0xf, 0xf, true));
}
__device__ __forceinline__ float dpp_shl1(float v) {  // lane n <- lane n+1
  return __int_as_float(__builtin_amdgcn_update_dpp(
      0, __float_as_int(v), 0x101, 0xf, 0xf, true));
}
template <int S>
__device__ __forceinline__ float dpp_shr(float v) {   // row_shr:S, zero-fill
  return __int_as_float(__builtin_amdgcn_update_dpp(
      0, __float_as_int(v), 0x110 | S, 0xf, 0xf, true));
}

// Wave-wide sum on the VALU pipe only (no DS-pipe shuffles). Proven R0 form.
__device__ __forceinline__ float wave_sum(float v) {
  v += dpp_shr<1>(v);
  v += dpp_shr<2>(v);
  v += dpp_shr<4>(v);
  v += dpp_shr<8>(v);
  const float a = __int_as_float(__builtin_amdgcn_readlane(__float_as_int(v), 15));
  const float b = __int_as_float(__builtin_amdgcn_readlane(__float_as_int(v), 31));
  const float c = __int_as_float(__builtin_amdgcn_readlane(__float_as_int(v), 47));
  const float d = __int_as_float(__builtin_amdgcn_readlane(__float_as_int(v), 63));
  return (a + b) + (c + d);
}

__device__ __forceinline__ float sum4(const float* buf) {
  const float4 a = *(const float4*)buf;  // one broadcast b128, conflict-free
  return (a.x + a.y) + (a.z + a.w);
}

// Horizontal 5-tap over one grid row's 1x3 values; neighbor columns come from
// adjacent lanes' registers via DPP (4 DPP + 12 VALU, no LDS).
__device__ __forceinline__ void horiz5(const float t[3], float H[3]) {
  float rv[7];  // rv[i] = value at column c0 + i - 2
  rv[2] = t[0]; rv[3] = t[1]; rv[4] = t[2];
  rv[0] = dpp_shr1(t[1]);  // left neighbor col c0-2
  rv[1] = dpp_shr1(t[2]);  // left neighbor col c0-1
  rv[5] = dpp_shl1(t[0]);  // right neighbor col c0+3
  rv[6] = dpp_shl1(t[1]);  // right neighbor col c0+4
#pragma unroll
  for (int k = 0; k < 3; ++k) {
    H[k] = rv[k + 2] + W1 * (rv[k + 1] + rv[k + 3]) + W2 * (rv[k] + rv[k + 4]);
  }
}

// Vertical 5-tap over the H-field for a 3-row tile: 4 halo rows via single
// ds_read_b128 each; own 3 rows from registers.
__device__ __forceinline__ void vert5x3(const float* __restrict__ hbuf, int ip,
                                        const float* __restrict__ own,  // [9]
                                        float* __restrict__ acc) {      // [9]
  const float4 m2 = *(const float4*)(hbuf + ip - 2 * SW);  // row r0-2
  const float4 m1 = *(const float4*)(hbuf + ip - 1 * SW);  // row r0-1
  const float4 p3 = *(const float4*)(hbuf + ip + 3 * SW);  // row r0+3
  const float4 p4 = *(const float4*)(hbuf + ip + 4 * SW);  // row r0+4
  // h[j][k]: H at row r0-2+j (j=0..6), col c0+k
  float h[7][3];
  h[0][0] = m2.x; h[0][1] = m2.y; h[0][2] = m2.z;
  h[1][0] = m1.x; h[1][1] = m1.y; h[1][2] = m1.z;
#pragma unroll
  for (int r = 0; r < 3; ++r)
#pragma unroll
    for (int k = 0; k < 3; ++k) h[2 + r][k] = own[r * 3 + k];
  h[5][0] = p3.x; h[5][1] = p3.y; h[5][2] = p3.z;
  h[6][0] = p4.x; h[6][1] = p4.y; h[6][2] = p4.z;
#pragma unroll
  for (int r = 0; r < 3; ++r) {
#pragma unroll
    for (int k = 0; k < 3; ++k) {
      acc[r * 3 + k] = h[2 + r][k] + W1 * (h[1 + r][k] + h[3 + r][k]) +
                       W2 * (h[r][k] + h[4 + r][k]);
    }
  }
}

// Exact diamond (L1 radius 3) conv for the EPILOGUE distance term, weights
// d*(e^{-5d}-eps), on raw v held as a 3-row tile (own rows in regs c[9],
// halo rows via b128 slot reads, horizontal extension via DPP). One-time.
__device__ __forceinline__ void conv_dist3(const float* __restrict__ pad, int ip,
                                           const float* __restrict__ c,
                                           float* __restrict__ out) {
  float acc[9];
#pragma unroll
  for (int i = 0; i < 9; ++i) acc[i] = 0.f;
#pragma unroll
  for (int rho = -3; rho <= 5; ++rho) {  // input row relative to tile row 0
    float t[3];
    if (rho >= 0 && rho <= 2) {
      t[0] = c[rho * 3]; t[1] = c[rho * 3 + 1]; t[2] = c[rho * 3 + 2];
    } else {
      const float4 q = *(const float4*)(pad + ip + rho * SW);
      t[0] = q.x; t[1] = q.y; t[2] = q.z;
    }
    float rowv[9];
    rowv[3] = t[0]; rowv[4] = t[1]; rowv[5] = t[2];
#pragma unroll
    for (int j = 0; j < 3; ++j) {
      rowv[j] = dpp_shr1(t[j]);
      rowv[6 + j] = dpp_shl1(t[j]);
    }
#pragma unroll
    for (int r = 0; r < 3; ++r) {
      int d = rho - r; d = d < 0 ? -d : d;
      if (d > 3) continue;
#pragma unroll
      for (int k = 0; k < 3; ++k) {
#pragma unroll
        for (int m = -3; m <= 3; ++m) {
          if (m < -(3 - d) || m > (3 - d)) continue;
          const int dist = d + (m < 0 ? -m : m);
          if (dist == 0) continue;
          const float wgt = (dist == 1) ? 6.7379370e-3f   // 1*(e^-5  - 1e-8)
                          : (dist == 2) ? 9.0779860e-5f   // 2*(e^-10 - 1e-8)
                                        : 8.8770696e-7f;  // 3*(e^-15 - 1e-8)
          acc[r * 3 + k] += wgt * rowv[k + m + 3];
        }
      }
    }
  }
#pragma unroll
  for (int i = 0; i < 9; ++i) out[i] = acc[i];
}

__global__ __launch_bounds__(NT, 1) void sinkhorn48(const float* __restrict__ x,
                                                    const float* __restrict__ y,
                                                    float* __restrict__ out) {
  __shared__ alignas(16) float bufU[FH * SW];  // H-field of u (4-float slots)
  __shared__ alignas(16) float bufV[FH * SW];  // H-field of v; raw v in epilogue
  __shared__ alignas(16) float rA[4];  // Su partials / x-sum / dist partials
  __shared__ alignas(16) float rB[4];  // Sv partials / y-sum
  __shared__ float vr[WIDTH];
  __shared__ float vc[WIDTH];

  const int tid = threadIdx.x;
  const int b = blockIdx.x;
  const int r0 = (tid >> 4) * 3;      // 16 row-groups of 3 rows
  const int tc = tid & 15;            // slot (column-group) index
  const int c0 = tc * 3;              // 3 adjacent columns per thread
  const int ip = (r0 + 3) * SW + tc * 4;  // 16B-aligned slot base (row r0)
  const int wid = tid >> 6;
  const int lane = tid & 63;

  // Zero both fields (halo rows + pad dwords must stay zero).
  for (int i = tid; i < FH * SW; i += NT) { bufU[i] = 0.f; bufV[i] = 0.f; }

  // Load this thread's 3x3 pixels of both images into registers.
  const float* xb = x + b * N;
  const float* yb = y + b * N;
  float xr[9], yr[9];
#pragma unroll
  for (int r = 0; r < 3; ++r)
#pragma unroll
    for (int k = 0; k < 3; ++k) {
      xr[r * 3 + k] = xb[(r0 + r) * WIDTH + c0 + k];
      yr[r * 3 + k] = yb[(r0 + r) * WIDTH + c0 + k];
    }
  {
    float sx = 0.f, sy = 0.f;
#pragma unroll
    for (int i = 0; i < 9; ++i) { sx += xr[i]; sy += yr[i]; }
    sx = wave_sum(sx); sy = wave_sum(sy);
    if (lane == 0) { rA[wid] = sx; rB[wid] = sy; }
  }
  __syncthreads();  // B0: publishes rA/rB partials + zeroed fields
  const float irx = __builtin_amdgcn_rcpf(sum4(rA));
  const float iry = __builtin_amdgcn_rcpf(sum4(rB));
#pragma unroll
  for (int i = 0; i < 9; ++i) { xr[i] *= irx; yr[i] *= iry; }

  float ur[9], hu[9], hv[9];
#pragma unroll
  for (int i = 0; i < 9; ++i) ur[i] = 1.0f / (float)N;
#pragma unroll
  for (int r = 0; r < 3; ++r) horiz5(ur + r * 3, hu + r * 3);
#pragma unroll
  for (int r = 0; r < 3; ++r)
    *(float4*)(bufU + ip + r * SW) = make_float4(hu[r * 3], hu[r * 3 + 1], hu[r * 3 + 2], 0.f);
  __syncthreads();  // B1: separates rA/rB reads above from rewrite below
  if (tid < NWAVE) rA[tid] = 1.0f / (float)NWAVE;  // Su(u0) = 1
  __syncthreads();  // B2: publishes rA + bufU interior

  float cc[9], vv[9];
  for (int iter = 0; iter < MAX_ITERS; ++iter) {
    const float Su = sum4(rA);   // published at last barrier; hides in vert5x3
    vert5x3(bufU, ip, hu, cc);   // local part of (u @ K')
    const float base = EPS * Su;  // exact rank-1 eps*J far field
    float pv = 0.f;
#pragma unroll
    for (int i = 0; i < 9; ++i) {
      vv[i] = yr[i] * __builtin_amdgcn_rcpf(base + cc[i]);
      pv += vv[i];
    }
#pragma unroll
    for (int r = 0; r < 3; ++r) horiz5(vv + r * 3, hv + r * 3);
#pragma unroll
    for (int r = 0; r < 3; ++r)
      *(float4*)(bufV + ip + r * SW) = make_float4(hv[r * 3], hv[r * 3 + 1], hv[r * 3 + 2], 0.f);
    pv = wave_sum(pv);
    if (lane == 0) rB[wid] = pv;
    __syncthreads();  // A: publishes bufV (H of v) + Sv partials

    const float Sv = sum4(rB);  // hides behind vert5x3 reads
    vert5x3(bufV, ip, hv, cc);
    const float base2 = EPS * Sv;
    float psu = 0.f;
#pragma unroll
    for (int i = 0; i < 9; ++i) {
      const float un = xr[i] * __builtin_amdgcn_rcpf(base2 + cc[i]);
      ur[i] = un;
      psu += un;
    }
#pragma unroll
    for (int r = 0; r < 3; ++r) horiz5(ur + r * 3, hu + r * 3);
#pragma unroll
    for (int r = 0; r < 3; ++r)
      *(float4*)(bufU + ip + r * SW) = make_float4(hu[r * 3], hu[r * 3 + 1], hu[r * 3 + 2], 0.f);
    psu = wave_sum(psu);
    if (lane == 0) rA[wid] = psu;
    __syncthreads();  // B: publishes bufU (H of u) + Su partials
  }

  // Final v from converged u.
  const float SuF = sum4(rA);
  vert5x3(bufU, ip, hu, cc);
  const float base = EPS * SuF;
#pragma unroll
  for (int i = 0; i < 9; ++i) vv[i] = yr[i] * __builtin_amdgcn_rcpf(base + cc[i]);
#pragma unroll
  for (int r = 0; r < 3; ++r)  // raw v for the epilogue (halo rows still zero)
    *(float4*)(bufV + ip + r * SW) = make_float4(vv[r * 3], vv[r * 3 + 1], vv[r * 3 + 2], 0.f);
  __syncthreads();

  // Row/col marginals of v for the separable eps*(C @ v) term (one-time).
  if (tid < WIDTH) {
    float s = 0.f;
    const float4* rp = (const float4*)(bufV + (tid + 3) * SW);
    for (int t = 0; t < 16; ++t) { const float4 q = rp[t]; s += q.x + q.y + q.z; }
    vr[tid] = s;
  } else if (tid >= 64 && tid < 64 + WIDTH) {
    const int c = tid - 64;
    float s = 0.f;
    const float* cp = bufV + 3 * SW + (c / 3) * 4 + (c % 3);
    for (int r = 0; r < WIDTH; ++r) s += cp[r * SW];
    vc[c] = s;
  }
  __syncthreads();

  // dist_b = sum_j u_j * ( eps*(Cv)_j + distance-weighted local conv ) — exact.
  float aD[9];
  conv_dist3(bufV, ip, vv, aD);
  float part = 0.f;
#pragma unroll
  for (int r = 0; r < 3; ++r) {
    const int rr = r0 + r;
    float cvr = 0.f;
    for (int q = 0; q < WIDTH; ++q) cvr += vr[q] * fabsf((float)(q - rr));
#pragma unroll
    for (int k = 0; k < 3; ++k) {
      const int ccol = c0 + k;
      float cvc = 0.f;
      for (int q = 0; q < WIDTH; ++q) cvc += vc[q] * fabsf((float)(q - ccol));
      part += ur[r * 3 + k] * (EPS * (cvr + cvc) + aD[r * 3 + k]);
    }
  }
  {
    const float p = wave_sum(part);
    if (lane == 0) rA[wid] = p;  // WAR on rA separated by the barriers above
  }
  __syncthreads();
  if (tid == 0) out[b] = sum4(rA);
}

extern "C" void kernel_launch(void* const* d_in, const int* in_sizes, int n_in,
                              void* d_out, int out_size, void* d_ws, size_t ws_size,
                              hipStream_t stream) {
  const float* x = (const float*)d_in[0];
  const float* y = (const float*)d_in[1];
  float* out = (float*)d_out;
  sinkhorn48<<<BATCH, NT, 0, stream>>>(x, y, out);
}

// Round 5
// 285.941 us; speedup vs baseline: 1.5529x; 1.0873x over previous
//
#include <hip/hip_runtime.h>

namespace {
constexpr int BATCH = 8;
constexpr int WIDTH = 48;
constexpr int N = WIDTH * WIDTH;   // 2304
constexpr int SW = 64;             // slot-row stride: 16 slots x 4 floats (16B each)
constexpr int FH = 54;             // 48 + 6 halo rows (radius-3 kept for epilogue conv)
constexpr int NT = 256;            // 4 waves (1/SIMD); 3x3 tile/thread
constexpr int NWAVE = NT / 64;     // 4
constexpr float EPS = 1e-8f;
constexpr int MAX_ITERS = 250;
// In-loop kernel K' = eps*J + e^{-5|dr|}e^{-5|dc|} with |dr|,|dc|<=2 (R4-verified,
// absmax 0.015625). eps*J is EXACT rank-1 via Su/Sv tracking (R3: dropping it
// diverges — it is the global connectivity, not a small correction).
// R4 post-mortem: half-phase is dependency-latency-bound (~25% issue occupancy,
// 1 wave/SIMD); this version shaves the serial wave-reduction tail
// (readlane chain -> row_bcast DPP finish) and interleaves reduce stages with
// independent conv work. Arithmetic unchanged except wave-sum add order
// (~1e-7 relative on Su/Sv, invisible at the 1.56e-2 bf16 ULP floor).
constexpr float W1 = 6.7379470e-3f;  // e^-5
constexpr float W2 = 4.5399930e-5f;  // e^-10
}

// DPP lane shifts within each 16-lane row; bound_ctrl=true zero-fills at the
// DPP-row boundary, which coincides exactly with the grid's column edge
// (16 col-groups per grid row), reproducing the zero column halo.
__device__ __forceinline__ float dpp_shr1(float v) {  // lane n <- lane n-1
  return __int_as_float(__builtin_amdgcn_update_dpp(
      0, __float_as_int(v), 0x111, 0xf, 0xf, true));
}
__device__ __forceinline__ float dpp_shl1(float v) {  // lane n <- lane n+1
  return __int_as_float(__builtin_amdgcn_update_dpp(
      0, __float_as_int(v), 0x101, 0xf, 0xf, true));
}
template <int S>
__device__ __forceinline__ float dpp_shr(float v) {   // row_shr:S, zero-fill
  return __int_as_float(__builtin_amdgcn_update_dpp(
      0, __float_as_int(v), 0x110 | S, 0xf, 0xf, true));
}
// Row-broadcast DPP (GCN/CDNA standard reduction finish): 0x142 = ROW_BCAST15
// (lane15 -> lanes16-31, lane47 -> lanes48-63), 0x143 = ROW_BCAST31
// (lane31 -> lanes32-63). bound_ctrl=true => unsourced lanes receive 0.
__device__ __forceinline__ float dpp_bcast15(float v) {
  return __int_as_float(__builtin_amdgcn_update_dpp(
      0, __float_as_int(v), 0x142, 0xf, 0xf, true));
}
__device__ __forceinline__ float dpp_bcast31(float v) {
  return __int_as_float(__builtin_amdgcn_update_dpp(
      0, __float_as_int(v), 0x143, 0xf, 0xf, true));
}

// Wave-wide sum, result valid in lane 63 only: 4 row-shr stages + 2 row_bcast
// adds. No readlane round-trips (they were ~4 serial VALU->SGPR hazards on the
// pre-barrier critical path). Sum order: (r3+r2)+(r1+r0) over 16-lane rows.
__device__ __forceinline__ float wave_sum63(float v) {
  v += dpp_shr<1>(v);
  v += dpp_shr<2>(v);
  v += dpp_shr<4>(v);
  v += dpp_shr<8>(v);
  v += dpp_bcast15(v);  // lane31 = r0+r1 ; lane63 = r3+r2
  v += dpp_bcast31(v);  // lane63 = (r3+r2)+(r1+r0)
  return v;
}

__device__ __forceinline__ float sum4(const float* buf) {
  const float4 a = *(const float4*)buf;  // one broadcast b128, conflict-free
  return (a.x + a.y) + (a.z + a.w);
}

// Horizontal 5-tap over one grid row's 1x3 values; neighbor columns come from
// adjacent lanes' registers via DPP (4 DPP + 12 VALU, no LDS).
__device__ __forceinline__ void horiz5(const float t[3], float H[3]) {
  float rv[7];  // rv[i] = value at column c0 + i - 2
  rv[2] = t[0]; rv[3] = t[1]; rv[4] = t[2];
  rv[0] = dpp_shr1(t[1]);  // left neighbor col c0-2
  rv[1] = dpp_shr1(t[2]);  // left neighbor col c0-1
  rv[5] = dpp_shl1(t[0]);  // right neighbor col c0+3
  rv[6] = dpp_shl1(t[1]);  // right neighbor col c0+4
#pragma unroll
  for (int k = 0; k < 3; ++k) {
    H[k] = rv[k + 2] + W1 * (rv[k + 1] + rv[k + 3]) + W2 * (rv[k] + rv[k + 4]);
  }
}

// Vertical 5-tap over the H-field for a 3-row tile: 4 halo rows via single
// ds_read_b128 each; own 3 rows from registers.
__device__ __forceinline__ void vert5x3(const float* __restrict__ hbuf, int ip,
                                        const float* __restrict__ own,  // [9]
                                        float* __restrict__ acc) {      // [9]
  const float4 m2 = *(const float4*)(hbuf + ip - 2 * SW);  // row r0-2
  const float4 m1 = *(const float4*)(hbuf + ip - 1 * SW);  // row r0-1
  const float4 p3 = *(const float4*)(hbuf + ip + 3 * SW);  // row r0+3
  const float4 p4 = *(const float4*)(hbuf + ip + 4 * SW);  // row r0+4
  // h[j][k]: H at row r0-2+j (j=0..6), col c0+k
  float h[7][3];
  h[0][0] = m2.x; h[0][1] = m2.y; h[0][2] = m2.z;
  h[1][0] = m1.x; h[1][1] = m1.y; h[1][2] = m1.z;
#pragma unroll
  for (int r = 0; r < 3; ++r)
#pragma unroll
    for (int k = 0; k < 3; ++k) h[2 + r][k] = own[r * 3 + k];
  h[5][0] = p3.x; h[5][1] = p3.y; h[5][2] = p3.z;
  h[6][0] = p4.x; h[6][1] = p4.y; h[6][2] = p4.z;
#pragma unroll
  for (int r = 0; r < 3; ++r) {
#pragma unroll
    for (int k = 0; k < 3; ++k) {
      acc[r * 3 + k] = h[2 + r][k] + W1 * (h[1 + r][k] + h[3 + r][k]) +
                       W2 * (h[r][k] + h[4 + r][k]);
    }
  }
}

// Exact diamond (L1 radius 3) conv for the EPILOGUE distance term, weights
// d*(e^{-5d}-eps), on raw v held as a 3-row tile (own rows in regs c[9],
// halo rows via b128 slot reads, horizontal extension via DPP). One-time.
__device__ __forceinline__ void conv_dist3(const float* __restrict__ pad, int ip,
                                           const float* __restrict__ c,
                                           float* __restrict__ out) {
  float acc[9];
#pragma unroll
  for (int i = 0; i < 9; ++i) acc[i] = 0.f;
#pragma unroll
  for (int rho = -3; rho <= 5; ++rho) {  // input row relative to tile row 0
    float t[3];
    if (rho >= 0 && rho <= 2) {
      t[0] = c[rho * 3]; t[1] = c[rho * 3 + 1]; t[2] = c[rho * 3 + 2];
    } else {
      const float4 q = *(const float4*)(pad + ip + rho * SW);
      t[0] = q.x; t[1] = q.y; t[2] = q.z;
    }
    float rowv[9];
    rowv[3] = t[0]; rowv[4] = t[1]; rowv[5] = t[2];
#pragma unroll
    for (int j = 0; j < 3; ++j) {
      rowv[j] = dpp_shr1(t[j]);
      rowv[6 + j] = dpp_shl1(t[j]);
    }
#pragma unroll
    for (int r = 0; r < 3; ++r) {
      int d = rho - r; d = d < 0 ? -d : d;
      if (d > 3) continue;
#pragma unroll
      for (int k = 0; k < 3; ++k) {
#pragma unroll
        for (int m = -3; m <= 3; ++m) {
          if (m < -(3 - d) || m > (3 - d)) continue;
          const int dist = d + (m < 0 ? -m : m);
          if (dist == 0) continue;
          const float wgt = (dist == 1) ? 6.7379370e-3f   // 1*(e^-5  - 1e-8)
                          : (dist == 2) ? 9.0779860e-5f   // 2*(e^-10 - 1e-8)
                                        : 8.8770696e-7f;  // 3*(e^-15 - 1e-8)
          acc[r * 3 + k] += wgt * rowv[k + m + 3];
        }
      }
    }
  }
#pragma unroll
  for (int i = 0; i < 9; ++i) out[i] = acc[i];
}

__global__ __launch_bounds__(NT, 1) void sinkhorn48(const float* __restrict__ x,
                                                    const float* __restrict__ y,
                                                    float* __restrict__ out) {
  __shared__ alignas(16) float bufU[FH * SW];  // H-field of u (4-float slots)
  __shared__ alignas(16) float bufV[FH * SW];  // H-field of v; raw v in epilogue
  __shared__ alignas(16) float rA[4];  // Su partials / x-sum / dist partials
  __shared__ alignas(16) float rB[4];  // Sv partials / y-sum
  __shared__ float vr[WIDTH];
  __shared__ float vc[WIDTH];

  const int tid = threadIdx.x;
  const int b = blockIdx.x;
  const int r0 = (tid >> 4) * 3;      // 16 row-groups of 3 rows
  const int tc = tid & 15;            // slot (column-group) index
  const int c0 = tc * 3;              // 3 adjacent columns per thread
  const int ip = (r0 + 3) * SW + tc * 4;  // 16B-aligned slot base (row r0)
  const int wid = tid >> 6;
  const int lane = tid & 63;

  // Zero both fields (halo rows + pad dwords must stay zero).
  for (int i = tid; i < FH * SW; i += NT) { bufU[i] = 0.f; bufV[i] = 0.f; }

  // Load this thread's 3x3 pixels of both images into registers.
  const float* xb = x + b * N;
  const float* yb = y + b * N;
  float xr[9], yr[9];
#pragma unroll
  for (int r = 0; r < 3; ++r)
#pragma unroll
    for (int k = 0; k < 3; ++k) {
      xr[r * 3 + k] = xb[(r0 + r) * WIDTH + c0 + k];
      yr[r * 3 + k] = yb[(r0 + r) * WIDTH + c0 + k];
    }
  {
    float sx = 0.f, sy = 0.f;
#pragma unroll
    for (int i = 0; i < 9; ++i) { sx += xr[i]; sy += yr[i]; }
    sx = wave_sum63(sx); sy = wave_sum63(sy);
    if (lane == 63) { rA[wid] = sx; rB[wid] = sy; }
  }
  __syncthreads();  // B0: publishes rA/rB partials + zeroed fields
  const float irx = __builtin_amdgcn_rcpf(sum4(rA));
  const float iry = __builtin_amdgcn_rcpf(sum4(rB));
#pragma unroll
  for (int i = 0; i < 9; ++i) { xr[i] *= irx; yr[i] *= iry; }

  float ur[9], hu[9], hv[9];
#pragma unroll
  for (int i = 0; i < 9; ++i) ur[i] = 1.0f / (float)N;
#pragma unroll
  for (int r = 0; r < 3; ++r) horiz5(ur + r * 3, hu + r * 3);
#pragma unroll
  for (int r = 0; r < 3; ++r)
    *(float4*)(bufU + ip + r * SW) = make_float4(hu[r * 3], hu[r * 3 + 1], hu[r * 3 + 2], 0.f);
  __syncthreads();  // B1: separates rA/rB reads above from rewrite below
  if (tid < NWAVE) rA[tid] = 1.0f / (float)NWAVE;  // Su(u0) = 1
  __syncthreads();  // B2: publishes rA + bufU interior

  float cc[9], vv[9];
  for (int iter = 0; iter < MAX_ITERS; ++iter) {
    const float Su = sum4(rA);   // b128 issued right after barrier; hides in vert
    vert5x3(bufU, ip, hu, cc);   // local part of (u @ K')
    const float base = EPS * Su;  // exact rank-1 eps*J far field
    float pv = 0.f;
#pragma unroll
    for (int i = 0; i < 9; ++i) {
      vv[i] = yr[i] * __builtin_amdgcn_rcpf(base + cc[i]);
      pv += vv[i];
    }
    // Reduction stages interleaved with independent horiz/store work so the
    // DPP-hazard bubbles overlap real work instead of stacking pre-barrier.
    pv += dpp_shr<1>(pv);
    horiz5(vv + 0, hv + 0);
    *(float4*)(bufV + ip + 0 * SW) = make_float4(hv[0], hv[1], hv[2], 0.f);
    pv += dpp_shr<2>(pv);
    horiz5(vv + 3, hv + 3);
    *(float4*)(bufV + ip + 1 * SW) = make_float4(hv[3], hv[4], hv[5], 0.f);
    pv += dpp_shr<4>(pv);
    horiz5(vv + 6, hv + 6);
    *(float4*)(bufV + ip + 2 * SW) = make_float4(hv[6], hv[7], hv[8], 0.f);
    pv += dpp_shr<8>(pv);
    pv += dpp_bcast15(pv);
    pv += dpp_bcast31(pv);
    if (lane == 63) rB[wid] = pv;
    __syncthreads();  // A: publishes bufV (H of v) + Sv partials

    const float Sv = sum4(rB);  // hides behind vert5x3 reads
    vert5x3(bufV, ip, hv, cc);
    const float base2 = EPS * Sv;
    float psu = 0.f;
#pragma unroll
    for (int i = 0; i < 9; ++i) {
      const float un = xr[i] * __builtin_amdgcn_rcpf(base2 + cc[i]);
      ur[i] = un;
      psu += un;
    }
    psu += dpp_shr<1>(psu);
    horiz5(ur + 0, hu + 0);
    *(float4*)(bufU + ip + 0 * SW) = make_float4(hu[0], hu[1], hu[2], 0.f);
    psu += dpp_shr<2>(psu);
    horiz5(ur + 3, hu + 3);
    *(float4*)(bufU + ip + 1 * SW) = make_float4(hu[3], hu[4], hu[5], 0.f);
    psu += dpp_shr<4>(psu);
    horiz5(ur + 6, hu + 6);
    *(float4*)(bufU + ip + 2 * SW) = make_float4(hu[6], hu[7], hu[8], 0.f);
    psu += dpp_shr<8>(psu);
    psu += dpp_bcast15(psu);
    psu += dpp_bcast31(psu);
    if (lane == 63) rA[wid] = psu;
    __syncthreads();  // B: publishes bufU (H of u) + Su partials
  }

  // Final v from converged u.
  const float SuF = sum4(rA);
  vert5x3(bufU, ip, hu, cc);
  const float base = EPS * SuF;
#pragma unroll
  for (int i = 0; i < 9; ++i) vv[i] = yr[i] * __builtin_amdgcn_rcpf(base + cc[i]);
#pragma unroll
  for (int r = 0; r < 3; ++r)  // raw v for the epilogue (halo rows still zero)
    *(float4*)(bufV + ip + r * SW) = make_float4(vv[r * 3], vv[r * 3 + 1], vv[r * 3 + 2], 0.f);
  __syncthreads();

  // Row/col marginals of v for the separable eps*(C @ v) term (one-time).
  if (tid < WIDTH) {
    float s = 0.f;
    const float4* rp = (const float4*)(bufV + (tid + 3) * SW);
    for (int t = 0; t < 16; ++t) { const float4 q = rp[t]; s += q.x + q.y + q.z; }
    vr[tid] = s;
  } else if (tid >= 64 && tid < 64 + WIDTH) {
    const int c = tid - 64;
    float s = 0.f;
    const float* cp = bufV + 3 * SW + (c / 3) * 4 + (c % 3);
    for (int r = 0; r < WIDTH; ++r) s += cp[r * SW];
    vc[c] = s;
  }
  __syncthreads();

  // dist_b = sum_j u_j * ( eps*(Cv)_j + distance-weighted local conv ) — exact.
  float aD[9];
  conv_dist3(bufV, ip, vv, aD);
  float part = 0.f;
#pragma unroll
  for (int r = 0; r < 3; ++r) {
    const int rr = r0 + r;
    float cvr = 0.f;
    for (int q = 0; q < WIDTH; ++q) cvr += vr[q] * fabsf((float)(q - rr));
#pragma unroll
    for (int k = 0; k < 3; ++k) {
      const int ccol = c0 + k;
      float cvc = 0.f;
      for (int q = 0; q < WIDTH; ++q) cvc += vc[q] * fabsf((float)(q - ccol));
      part += ur[r * 3 + k] * (EPS * (cvr + cvc) + aD[r * 3 + k]);
    }
  }
  {
    const float p = wave_sum63(part);
    if (lane == 63) rA[wid] = p;  // WAR on rA separated by the barriers above
  }
  __syncthreads();
  if (tid == 0) out[b] = sum4(rA);
}

extern "C" void kernel_launch(void* const* d_in, const int* in_sizes, int n_in,
                              void* d_out, int out_size, void* d_ws, size_t ws_size,
                              hipStream_t stream) {
  const float* x = (const float*)d_in[0];
  const float* y = (const float*)d_in[1];
  float* out = (float*)d_out;
  sinkhorn48<<<BATCH, NT, 0, stream>>>(x, y, out);
}